// Round 11
// baseline (836.039 us; speedup 1.0000x reference)
//
#include <hip/hip_runtime.h>
#include <hip/hip_bf16.h>

#define IN_CH 64
#define HID 32
#define HEADS 4
#define C1 128   // HEADS*HID
#define OUTC 32
#define NEGSLOPE 0.2f

__device__ __forceinline__ float lrelu(float v) { return v > 0.f ? v : NEGSLOPE * v; }
__device__ __forceinline__ float elu(float v) { return v > 0.f ? v : __expf(v) - 1.f; }

// edge layout L1: [src(E) | dst(E)] halves, int32 (canonical row-major (2,E))
__device__ __forceinline__ int esrc(const int* __restrict__ w, int E, int e) { return w[e]; }
__device__ __forceinline__ int edst(const int* __restrict__ w, int E, int e) { return w[E + e]; }

// ---------------- CSR build ----------------

__global__ void k_degree(const int* __restrict__ w, int* __restrict__ deg, int E) {
  int stride = gridDim.x * blockDim.x;
  for (int e = blockIdx.x * blockDim.x + threadIdx.x; e < E; e += stride)
    atomicAdd(&deg[edst(w, E, e)], 1);
}

__global__ void k_scan1(const int* __restrict__ deg, int* __restrict__ rp,
                        int* __restrict__ bsums, int n) {
  __shared__ int sm[256];
  int t = threadIdx.x;
  int i = blockIdx.x * 256 + t;
  int v = (i < n) ? deg[i] : 0;
  sm[t] = v;
  __syncthreads();
  #pragma unroll
  for (int off = 1; off < 256; off <<= 1) {
    int tv = (t >= off) ? sm[t - off] : 0;
    __syncthreads();
    sm[t] += tv;
    __syncthreads();
  }
  if (i < n) rp[i] = sm[t] - v;
  if (t == 255) bsums[blockIdx.x] = sm[255];
}

__global__ void k_scan2(int* __restrict__ bs, int nc) {
  __shared__ int sm[512];
  int t = threadIdx.x;
  int v = (t < nc) ? bs[t] : 0;
  sm[t] = v;
  __syncthreads();
  #pragma unroll
  for (int off = 1; off < 512; off <<= 1) {
    int tv = (t >= off) ? sm[t - off] : 0;
    __syncthreads();
    sm[t] += tv;
    __syncthreads();
  }
  if (t < nc) bs[t] = sm[t] - v;
}

__global__ void k_scan3(int* __restrict__ rp, int* __restrict__ cur,
                        const int* __restrict__ bs, int n, int E) {
  int i = blockIdx.x * 256 + threadIdx.x;
  if (i < n) {
    int r = rp[i] + bs[blockIdx.x];
    rp[i] = r;
    cur[i] = r;
  }
  if (i == 0) rp[n] = E;
}

__global__ void k_scatter(const int* __restrict__ w, int* __restrict__ cur,
                          int* __restrict__ csr, int E) {
  int stride = gridDim.x * blockDim.x;
  for (int e = blockIdx.x * blockDim.x + threadIdx.x; e < E; e += stride) {
    int d = edst(w, E, e);
    int s = esrc(w, E, e);
    int p = atomicAdd(&cur[d], 1);
    csr[p] = s;
  }
}

// ---------------- k1: h = x@W1, plus per-node attention logits ----------------
__global__ __launch_bounds__(128) void k1(
    const float* __restrict__ x, const float* __restrict__ W1,
    const float* __restrict__ attS, const float* __restrict__ attD,
    float* __restrict__ h, float* __restrict__ alS, float* __restrict__ alD, int nN) {
  __shared__ float xrow[IN_CH];
  __shared__ float hrow[C1];
  int n = blockIdx.x;
  if (n >= nN) return;
  int j = threadIdx.x;
  if (j < IN_CH) xrow[j] = x[(size_t)n * IN_CH + j];
  __syncthreads();
  float a = 0.f;
  for (int k = 0; k < IN_CH; ++k) a += xrow[k] * W1[k * C1 + j];
  h[(size_t)n * C1 + j] = a;
  hrow[j] = a;
  __syncthreads();
  if (j < 2 * HEADS) {
    int g = j >> 1;
    int isD = j & 1;
    const float* att = isD ? attD : attS;
    float s = 0.f;
    for (int c = 0; c < HID; ++c) s += hrow[g * HID + c] * att[g * HID + c];
    if (isD) alD[(size_t)n * HEADS + g] = s;
    else     alS[(size_t)n * HEADS + g] = s;
  }
}

// ---------------- k2: layer-1 softmax-aggregate + bias + ELU -> h1 ----------------
__global__ __launch_bounds__(256) void k2(
    const float* __restrict__ h, const float* __restrict__ alS, const float* __restrict__ alD,
    const int* __restrict__ rp, const int* __restrict__ csr,
    const float* __restrict__ b1, float* __restrict__ h1, int nN) {
  int t = blockIdx.x * 256 + threadIdx.x;
  if (t >= nN * HEADS) return;
  int n = t >> 2;       // node
  int g = t & 3;        // head
  int rs = rp[n], re = rp[n + 1];
  float ad = alD[(size_t)n * HEADS + g];
  float m = lrelu(alS[(size_t)n * HEADS + g] + ad);
  for (int i = rs; i < re; ++i) {
    int s = csr[i];
    m = fmaxf(m, lrelu(alS[(size_t)s * HEADS + g] + ad));
  }
  float acc[HID];
  #pragma unroll
  for (int c = 0; c < HID; ++c) acc[c] = 0.f;
  float denom = 0.f;
  {  // self-loop
    float w = __expf(lrelu(alS[(size_t)n * HEADS + g] + ad) - m);
    denom += w;
    const float* hrow = h + (size_t)n * C1 + g * HID;
    #pragma unroll
    for (int c = 0; c < HID; ++c) acc[c] += w * hrow[c];
  }
  for (int i = rs; i < re; ++i) {
    int s = csr[i];
    float w = __expf(lrelu(alS[(size_t)s * HEADS + g] + ad) - m);
    denom += w;
    const float* hrow = h + (size_t)s * C1 + g * HID;
    #pragma unroll
    for (int c = 0; c < HID; ++c) acc[c] += w * hrow[c];
  }
  float inv = 1.f / denom;
  #pragma unroll
  for (int c = 0; c < HID; ++c) {
    float v = acc[c] * inv + b1[g * HID + c];
    h1[(size_t)n * C1 + g * HID + c] = elu(v);
  }
}

// ---------------- k3: h2 = h1@W2 ----------------
__global__ __launch_bounds__(256) void k3(
    const float* __restrict__ h1, const float* __restrict__ W2,
    float* __restrict__ h2, int nN) {
  int t = blockIdx.x * 256 + threadIdx.x;
  if (t >= nN * OUTC) return;
  int n = t >> 5;
  int j = t & 31;
  const float* row = h1 + (size_t)n * C1;
  float a = 0.f;
  for (int k = 0; k < C1; ++k) a += row[k] * W2[k * OUTC + j];
  h2[(size_t)n * OUTC + j] = a;
}

// ---------------- k3b: layer-2 logits ----------------
__global__ __launch_bounds__(256) void k3b(
    const float* __restrict__ h2, const float* __restrict__ attS2,
    const float* __restrict__ attD2,
    float* __restrict__ alS2, float* __restrict__ alD2, int nN) {
  int n = blockIdx.x * 256 + threadIdx.x;
  if (n >= nN) return;
  const float* row = h2 + (size_t)n * OUTC;
  float s = 0.f, d = 0.f;
  for (int j = 0; j < OUTC; ++j) {
    s += row[j] * attS2[j];
    d += row[j] * attD2[j];
  }
  alS2[n] = s;
  alD2[n] = d;
}

// ---------------- k4: layer-2 softmax-aggregate + bias -> out (FP32!) ----------------
__global__ __launch_bounds__(256) void k4(
    const float* __restrict__ h2, const float* __restrict__ alS2, const float* __restrict__ alD2,
    const int* __restrict__ rp, const int* __restrict__ csr,
    const float* __restrict__ b2, float* __restrict__ out, int nN) {
  int n = blockIdx.x * 256 + threadIdx.x;
  if (n >= nN) return;
  int rs = rp[n], re = rp[n + 1];
  float ad = alD2[n];
  float m = lrelu(alS2[n] + ad);
  for (int i = rs; i < re; ++i) m = fmaxf(m, lrelu(alS2[csr[i]] + ad));
  float acc[OUTC];
  #pragma unroll
  for (int c = 0; c < OUTC; ++c) acc[c] = 0.f;
  float denom = 0.f;
  {  // self-loop
    float w = __expf(lrelu(alS2[n] + ad) - m);
    denom += w;
    const float* row = h2 + (size_t)n * OUTC;
    #pragma unroll
    for (int c = 0; c < OUTC; ++c) acc[c] += w * row[c];
  }
  for (int i = rs; i < re; ++i) {
    int s = csr[i];
    float w = __expf(lrelu(alS2[s] + ad) - m);
    denom += w;
    const float* row = h2 + (size_t)s * OUTC;
    #pragma unroll
    for (int c = 0; c < OUTC; ++c) acc[c] += w * row[c];
  }
  float inv = 1.f / denom;
  #pragma unroll
  for (int c = 0; c < OUTC; ++c)
    out[(size_t)n * OUTC + c] = acc[c] * inv + b2[c];
}

// ---------------- launch ----------------

extern "C" void kernel_launch(void* const* d_in, const int* in_sizes, int n_in,
                              void* d_out, int out_size, void* d_ws, size_t ws_size,
                              hipStream_t stream) {
  // Host tripwires (validated R7)
  {
    const int expect[10] = {6400000, 3200000, 8192, 128, 128, 128, 4096, 32, 32, 32};
    bool ok = (n_in == 10) && (out_size == 3200000);
    for (int i = 0; i < 10 && ok; ++i) ok = (in_sizes[i] == expect[i]);
    if (!ok) { *(volatile int*)0 = 1; }
  }

  const float* x     = (const float*)d_in[0];
  const int*   ew    = (const int*)d_in[1];
  const float* W1    = (const float*)d_in[2];
  const float* attS1 = (const float*)d_in[3];
  const float* attD1 = (const float*)d_in[4];
  const float* b1    = (const float*)d_in[5];
  const float* W2    = (const float*)d_in[6];
  const float* attS2 = (const float*)d_in[7];
  const float* attD2 = (const float*)d_in[8];
  const float* b2    = (const float*)d_in[9];
  float* out = (float*)d_out;   // reference output dtype is float32

  const int nN = in_sizes[0] / IN_CH;   // 100000
  const int E  = in_sizes[1] / 2;       // 1600000

  auto ALN = [](size_t v) { return (v + 255) & ~(size_t)255; };
  char* p = (char*)d_ws;
  float* h    = (float*)p; p += ALN((size_t)nN * C1 * 4);
  float* h1   = (float*)p; p += ALN((size_t)nN * C1 * 4);
  float* alS1v= (float*)p; p += ALN((size_t)nN * HEADS * 4);
  float* alD1v= (float*)p; p += ALN((size_t)nN * HEADS * 4);
  float* h2v  = (float*)p; p += ALN((size_t)nN * OUTC * 4);
  float* alS2v= (float*)p; p += ALN((size_t)nN * 4);
  float* alD2v= (float*)p; p += ALN((size_t)nN * 4);
  int* deg    = (int*)p;   p += ALN((size_t)nN * 4);
  int* rp     = (int*)p;   p += ALN((size_t)(nN + 1) * 4);
  int* cur    = (int*)p;   p += ALN((size_t)nN * 4);
  int* bs     = (int*)p;   p += ALN(1024 * 4);
  int* csr    = (int*)p;   p += ALN((size_t)E * 4);
  if ((size_t)(p - (char*)d_ws) > ws_size) { *(volatile int*)0 = 2; }

  const int nChunks = (nN + 255) / 256;  // 391

  hipMemsetAsync(deg, 0, (size_t)nN * 4, stream);
  k_degree<<<1024, 256, 0, stream>>>(ew, deg, E);
  k_scan1<<<nChunks, 256, 0, stream>>>(deg, rp, bs, nN);
  k_scan2<<<1, 512, 0, stream>>>(bs, nChunks);
  k_scan3<<<nChunks, 256, 0, stream>>>(rp, cur, bs, nN, E);
  k_scatter<<<1024, 256, 0, stream>>>(ew, cur, csr, E);
  k1<<<nN, 128, 0, stream>>>(x, W1, attS1, attD1, h, alS1v, alD1v, nN);
  k2<<<(nN * HEADS + 255) / 256, 256, 0, stream>>>(h, alS1v, alD1v, rp, csr, b1, h1, nN);
  k3<<<(nN * OUTC + 255) / 256, 256, 0, stream>>>(h1, W2, h2v, nN);
  k3b<<<nChunks, 256, 0, stream>>>(h2v, attS2, attD2, alS2v, alD2v, nN);
  k4<<<nChunks, 256, 0, stream>>>(h2v, alS2v, alD2v, rp, csr, b2, out, nN);
}